// Round 14
// baseline (376.579 us; speedup 1.0000x reference)
//
#include <hip/hip_runtime.h>
#include <hip/hip_bf16.h>

// TransMatch round 20:
//  - k_score: phase pairs merged (8 phases -> 4 mega-phases per 2-K-tile
//    iteration). Each mega-phase: {read A-half + BOTH B-halves + stage both
//    halves of one prefetch tile; bar; 32 MFMA; bar}. Barriers per block
//    65 -> 33. Addressing/swizzle/load-order/register-lifetimes identical
//    to round-19 verified code; vmcnt invariants mirrored exactly
//    (vmcnt(4) at MP2 [vmcnt(0) at it==3] and MP4 [it<3]).
//  - Everything else byte-identical to round 19 (371.5 us verified).
//
// ws layout (float words):
//   Qh   fp16 [2][8][3072][512]  @ 0          = 12,582,912 f
//   sig  f32  [8][192][192]      @ 12,582,912 =    294,912 f
//   xkey u32  [8][512][192]      @ 12,877,824 =    786,432 f
//   xh   fp16 [8][512][192]      @ 13,664,256 =    393,216 f
//   w2h  fp16 [8][2048][192]     @ 14,057,472 =  1,572,864 f
//   hb   fp16 [8][512][2048]     @ 15,630,336 =  4,194,304 f   (w0h overlaid until k_fc2)
//   bn2sum f32 [8][2048]         @ 19,824,640 =     16,384 f
//   bn2sq  f32 [8][2048]         @ 19,841,024 =     16,384 f
//   bn1acc f32 [8][2]            @ 19,857,408 =         16 f
//   ybuf f32 [8][512]            @ 19,857,424 =      4,096 f

#define EPS_ 1e-5f

typedef __attribute__((ext_vector_type(8))) _Float16 fp16x8;
typedef __attribute__((ext_vector_type(4)))  float   f32x4;
typedef __attribute__((ext_vector_type(16))) float   f32x16;

__device__ __forceinline__ unsigned fkey(float f) {
    unsigned u = __float_as_uint(f);
    return (u & 0x80000000u) ? ~u : (u | 0x80000000u);
}
__device__ __forceinline__ float funkey(unsigned k) {
    return (k & 0x80000000u) ? __uint_as_float(k & 0x7FFFFFFFu)
                             : __uint_as_float(~k);
}
__device__ __forceinline__ void gld16(const void* gp, void* lp) {
    __builtin_amdgcn_global_load_lds(
        (const __attribute__((address_space(1))) unsigned*)gp,
        (__attribute__((address_space(3))) unsigned*)lp, 16, 0, 0);
}

// ---- K_prep: sigmoid(se) + w2 cvt + w0 cvt(pre-swizzled) + zeroing ----
__global__ __launch_bounds__(256) void k_prep(const float* __restrict__ se,
                                              float* __restrict__ sig,
                                              const float* __restrict__ w2,
                                              _Float16* __restrict__ w2h,
                                              unsigned* __restrict__ xkey,
                                              float* __restrict__ bn2z,
                                              const float* __restrict__ w0,
                                              _Float16* __restrict__ w0h) {
    int b = blockIdx.x;
    int tid = threadIdx.x;
    if (b < 768) {              // w2 fp32 -> fp16: 786432 float4 total, 4/thread
        size_t base = (size_t)b * 1024 + tid;     // float4 units
        #pragma unroll
        for (int k = 0; k < 4; k++) {
            size_t i = base + k * 256;
            float4 v = ((const float4*)w2)[i];
            _Float16 h[4] = {(_Float16)v.x, (_Float16)v.y, (_Float16)v.z, (_Float16)v.w};
            ((uint2*)w2h)[i] = *(uint2*)h;
        }
    } else if (b < 1056) {      // sigmoid (294912 elems, 288 blocks)
        int i = (b - 768) * 256 + tid;
        float4 v = *(const float4*)(se + (size_t)i * 4);
        float4 o;
        o.x = 1.f / (1.f + __expf(-v.x));
        o.y = 1.f / (1.f + __expf(-v.y));
        o.z = 1.f / (1.f + __expf(-v.z));
        o.w = 1.f / (1.f + __expf(-v.w));
        *(float4*)(sig + (size_t)i * 4) = o;
    } else if (b < 1248) {      // xkey zero: 786432 words, 192 blocks
        int i = (b - 1056) * 256 + tid;
        uint4 z = {0u, 0u, 0u, 0u};
        uint4* p = (uint4*)xkey + (size_t)i * 4;
        p[0] = z; p[1] = z; p[2] = z; p[3] = z;
    } else if (b < 1281) {      // bn2sum/bn2sq/bn1acc zero (33 blocks)
        int i = (b - 1248) * 256 + tid;
        if (i < 8196) {
            float4 z = {0.f, 0.f, 0.f, 0.f};
            *(float4*)(bn2z + (size_t)i * 4) = z;
        }
    } else {                    // w0 cvt: chunk ((l*8+ks)*512+e)*8 + (ch^(e&7))
        int g = (b - 1281) * 256 + tid;   // 0..262143
        int l  = g >> 15;
        int r  = g & 32767;
        int ks = r >> 12;
        int rr = r & 4095;
        int e  = rr >> 3;
        int ch = rr & 7;
        const float* src = w0 + (size_t)l * 262144 + (size_t)e * 512 + ks * 64 + ch * 8;
        float4 v0 = *(const float4*)src;
        float4 v1 = *(const float4*)(src + 4);
        fp16x8 h;
        h[0] = (_Float16)v0.x; h[1] = (_Float16)v0.y; h[2] = (_Float16)v0.z; h[3] = (_Float16)v0.w;
        h[4] = (_Float16)v1.x; h[5] = (_Float16)v1.y; h[6] = (_Float16)v1.z; h[7] = (_Float16)v1.w;
        size_t dst = ((size_t)(l * 8 + ks) * 512 + e) * 8 + (ch ^ (e & 7));
        *(fp16x8*)(w0h + dst * 8) = h;
    }
}

// ---------------- K1: fc0 -- M=192 x N=128 x K=512 fp16 GEMM ----------------
// (round-14 verified body; LDS 80 KiB -> 2 blocks/CU; coalesced epilogue)
__global__ __launch_bounds__(512, 4) void k_fc0(const float* __restrict__ qfeat,
                                                const float* __restrict__ gfeat,
                                                const _Float16* __restrict__ w0h,
                                                const float* __restrict__ b0,
                                                _Float16* __restrict__ Qh) {
    int bid = blockIdx.x;
    int blo = bid & 7;
    int et  = (bid >> 3) & 3;
    int bhi = (bid >> 5) & 1;
    int sel = (bid >> 6) & 1;
    int l   = bid >> 7;
    int b   = blo + bhi * 8;

    const float* feat = sel ? gfeat : qfeat;
    const float* Af = feat + (size_t)b * 786432 + (size_t)l * 98304;

    __shared__ __align__(16) char smem[81920];
    // A: [2 buf][192 rows][128 B] @ 0 (49152); W: [2 buf][128 rows][128 B] @ 49152

    int tid = threadIdx.x;
    int lane = tid & 63;
    int w = tid >> 6;
    int wm = w >> 2, wn = w & 3;     // 2 x 4 wave grid
    int c = lane & 15;
    int hi4 = lane >> 4;

    // A staging: slot s (0..1535) -> chunk = s/192, t = s%192; 3 slots/thread.
    int s0 = tid, s1 = tid + 512, s2 = tid + 1024;
    int ch0 = s0 / 192, t0 = s0 - ch0 * 192;
    int ch1 = s1 / 192, t1 = s1 - ch1 * 192;
    int ch2 = s2 / 192, t2 = s2 - ch2 * 192;
    const float* ap0 = Af + ch0 * 1536 + t0;
    const float* ap1 = Af + ch1 * 1536 + t1;
    const float* ap2 = Af + ch2 * 1536 + t2;
    int aw0 = t0 * 128 + ((ch0 ^ (t0 & 7)) << 4);
    int aw1 = t1 * 128 + ((ch1 ^ (t1 & 7)) << 4);
    int aw2 = t2 * 128 + ((ch2 ^ (t2 & 7)) << 4);

    f32x4 acc[6][2];
    #pragma unroll
    for (int mi = 0; mi < 6; mi++)
        #pragma unroll
        for (int nj = 0; nj < 2; nj++)
            #pragma unroll
            for (int r = 0; r < 4; r++) acc[mi][nj][r] = 0.f;

    float rA[3][8];

    auto ALOAD = [&](int ks) {
        int off = ks * 12288;       // d0*192
        #pragma unroll
        for (int j = 0; j < 8; j++) rA[0][j] = ap0[off + j * 192];
        #pragma unroll
        for (int j = 0; j < 8; j++) rA[1][j] = ap1[off + j * 192];
        #pragma unroll
        for (int j = 0; j < 8; j++) rA[2][j] = ap2[off + j * 192];
    };
    auto WLOAD = [&](int ks, int buf) {
        const _Float16* wp = w0h + ((size_t)(l * 8 + ks) * 512 + et * 128) * 64;
        char* d = smem + 49152 + buf * 16384;
        #pragma unroll
        for (int p = 0; p < 2; p++)
            gld16(wp + (size_t)(tid + p * 512) * 8, d + (tid + p * 512) * 16);
    };
    auto AWRITE = [&](int buf) {
        char* db = smem + buf * 24576;
        fp16x8 h0, h1, h2;
        #pragma unroll
        for (int j = 0; j < 8; j++) h0[j] = (_Float16)rA[0][j];
        #pragma unroll
        for (int j = 0; j < 8; j++) h1[j] = (_Float16)rA[1][j];
        #pragma unroll
        for (int j = 0; j < 8; j++) h2[j] = (_Float16)rA[2][j];
        *(fp16x8*)(db + aw0) = h0;
        *(fp16x8*)(db + aw1) = h1;
        *(fp16x8*)(db + aw2) = h2;
    };
    auto COMPUTE = [&](int buf) {
        const char* Ab = smem + buf * 24576;
        const char* Wb = smem + 49152 + buf * 16384;
        fp16x8 afr[6][2], bfr[2][2];
        #pragma unroll
        for (int mi = 0; mi < 6; mi++) {
            int tr = wm * 96 + mi * 16 + c;
            #pragma unroll
            for (int k2 = 0; k2 < 2; k2++) {
                int ph = (k2 * 4 + hi4) ^ (tr & 7);
                afr[mi][k2] = *(const fp16x8*)(Ab + tr * 128 + ph * 16);
            }
        }
        #pragma unroll
        for (int nj = 0; nj < 2; nj++) {
            int er = wn * 32 + nj * 16 + c;
            #pragma unroll
            for (int k2 = 0; k2 < 2; k2++) {
                int ph = (k2 * 4 + hi4) ^ (er & 7);
                bfr[nj][k2] = *(const fp16x8*)(Wb + er * 128 + ph * 16);
            }
        }
        #pragma unroll
        for (int k2 = 0; k2 < 2; k2++)
            #pragma unroll
            for (int mi = 0; mi < 6; mi++)
                #pragma unroll
                for (int nj = 0; nj < 2; nj++)
                    acc[mi][nj] = __builtin_amdgcn_mfma_f32_16x16x32_f16(
                        afr[mi][k2], bfr[nj][k2], acc[mi][nj], 0, 0, 0);
    };

    // prologue: stage K-step 0
    ALOAD(0); WLOAD(0, 0); AWRITE(0);
    __syncthreads();
    #pragma unroll
    for (int ks = 0; ks < 8; ks++) {
        int cur = ks & 1, nxt = cur ^ 1;
        if (ks < 7) { ALOAD(ks + 1); WLOAD(ks + 1, nxt); }
        COMPUTE(cur);
        if (ks < 7) AWRITE(nxt);
        __syncthreads();
    }

    // ---- coalesced epilogue: acc+bias -> LDS [192][128] fp16 -> 16B stores
    __syncthreads();
    _Float16* lb = (_Float16*)smem;
    int rq = hi4 * 4;
    #pragma unroll
    for (int nj = 0; nj < 2; nj++) {
        int col = wn * 32 + nj * 16 + c;
        float bias = b0[l * 512 + et * 128 + col];
        #pragma unroll
        for (int mi = 0; mi < 6; mi++) {
            int tb = wm * 96 + mi * 16 + rq;
            #pragma unroll
            for (int r = 0; r < 4; r++)
                lb[(tb + r) * 128 + col] = (_Float16)(acc[mi][nj][r] + bias);
        }
    }
    __syncthreads();
    _Float16* Ob = Qh + ((size_t)(sel * 8 + l) * 16 + b) * 98304 + et * 128;
    #pragma unroll
    for (int p = 0; p < 6; p++) {
        int v = tid + p * 512;          // vec8 index, 0..3071
        int t = v >> 4;                 // row 0..191
        int e = (v & 15) * 8;           // col 0..120
        *(fp16x8*)(Ob + (size_t)t * 512 + e) = *(const fp16x8*)(lb + t * 128 + e);
    }
}

// ---------------- K2: score GEMM, 256x256 tile, 4 mega-phase pipeline ------
#define BARP() do { __builtin_amdgcn_s_barrier(); \
                    __builtin_amdgcn_sched_barrier(0); } while (0)

__global__ __launch_bounds__(512, 2) void k_score(const _Float16* __restrict__ Qh,
                                                  const float* __restrict__ sig,
                                                  unsigned* __restrict__ xkey,
                                                  int base) {
    int bid = blockIdx.x + base;
    int l = bid & 7;           // layer-per-XCD (grid total = 8 * 144)
    int tau = bid >> 3;        // 0..143
    int mt = tau % 12;
    int nt = tau / 12;
    int m0 = mt * 256, n0 = nt * 256;

    const char* Ag = (const char*)(Qh + (size_t)(8 + l) * 1572864);  // key
    const char* Bg = (const char*)(Qh + (size_t)l * 1572864);        // query

    __shared__ __align__(16) char smem[131072];

    int tid = threadIdx.x;
    int lane = tid & 63;
    int w = tid >> 6;          // 0..7
    int wm = w >> 2, wn = w & 3;
    int c = lane & 15;
    int hi4 = lane >> 4;       // 0..3

    // fragment ds-read addressing (swizzled)
    int pk0 = ((hi4)     ^ (c & 7)) * 16;   // ks=0 logical chunk ^ row&7
    int pk1 = ((4 + hi4) ^ (c & 7)) * 16;   // ks=1
    char* aBase = smem + wm * 16384 + c * 128;
    char* bBase = smem + 65536 + (wn >> 1) * 16384 + ((wn & 1) * 64 + c) * 128;

    // staging addressing: lane -> row (lane>>3), phys chunk (lane&7);
    // global source pre-applies the inverse swizzle.
    int rl = lane >> 3;
    int qsw = ((lane & 7) ^ rl) * 16;
    const char* Asrc = Ag + (size_t)(m0 + w * 8 + rl) * 1024 + qsw;
    const char* Bsrc = Bg + (size_t)(n0 + w * 8 + rl) * 1024 + qsw;
    char* aSt = smem + w * 1024;
    char* bSt = smem + 65536 + w * 1024;

    f32x4 acc[8][4];
    #pragma unroll
    for (int mi = 0; mi < 8; mi++)
        #pragma unroll
        for (int nj = 0; nj < 4; nj++)
            #pragma unroll
            for (int r = 0; r < 4; r++) acc[mi][nj][r] = 0.f;

    fp16x8 a[4][2], b01[2][2], b23[2][2];

    auto STA = [&](int t, int h) {   // stage A half-tile (16 KB, 2 loads/thread)
        if (t < 8) {
            const char* s = Asrc + (size_t)(h * 128) * 1024 + t * 128;
            char* d = aSt + (t & 1) * 32768 + h * 16384;
            gld16(s, d);
            gld16(s + 64 * 1024, d + 8192);
        }
    };
    auto STB = [&](int t, int h) {
        if (t < 8) {
            const char* s = Bsrc + (size_t)(h * 128) * 1024 + t * 128;
            char* d = bSt + (t & 1) * 32768 + h * 16384;
            gld16(s, d);
            gld16(s + 64 * 1024, d + 8192);
        }
    };
    auto LDA = [&](int t, int mh) {  // a[mi 0..3][ks] for mi = mh*4..mh*4+3
        const char* p = aBase + (t & 1) * 32768 + mh * 8192;
        #pragma unroll
        for (int m = 0; m < 4; m++) {
            a[m][0] = *(const fp16x8*)(p + m * 2048 + pk0);
            a[m][1] = *(const fp16x8*)(p + m * 2048 + pk1);
        }
    };
    auto LDB = [&](int t, int nh, fp16x8 (&bb)[2][2]) {
        const char* p = bBase + (t & 1) * 32768 + nh * 4096;
        #pragma unroll
        for (int n = 0; n < 2; n++) {
            bb[n][0] = *(const fp16x8*)(p + n * 2048 + pk0);
            bb[n][1] = *(const fp16x8*)(p + n * 2048 + pk1);
        }
    };
    auto MM = [&](int mh, int nh, fp16x8 (&bb)[2][2]) {
        #pragma unroll
        for (int ks = 0; ks < 2; ks++)
            #pragma unroll
            for (int m = 0; m < 4; m++)
                #pragma unroll
                for (int n = 0; n < 2; n++)
                    acc[mh * 4 + m][nh * 2 + n] = __builtin_amdgcn_mfma_f32_16x16x32_f16(
                        a[m][ks], bb[n][ks], acc[mh * 4 + m][nh * 2 + n], 0, 0, 0);
    };

    // prologue: tile0 (B then A), then B(1); leave B(1) (4 loads) in flight
    STB(0, 0); STB(0, 1); STA(0, 0); STA(0, 1); STB(1, 0); STB(1, 1);
    asm volatile("s_waitcnt vmcnt(4)");
    BARP();

    #pragma unroll
    for (int it = 0; it < 4; it++) {
        int T = 2 * it, U = 2 * it + 1;
        // MP1: T row-0 quadrants (A0 x B0,B1); stage A(U) both halves
        LDA(T, 0); LDB(T, 0, b01); LDB(T, 1, b23); STA(U, 0); STA(U, 1); BARP();
        __builtin_amdgcn_s_setprio(1); MM(0, 0, b01); MM(0, 1, b23); __builtin_amdgcn_s_setprio(0); BARP();
        // MP2: T row-1 (A1 x B0,B1); stage B(T+2) both halves; wait A(U)
        LDA(T, 1); STB(T + 2, 0); STB(T + 2, 1); BARP();
        __builtin_amdgcn_s_setprio(1); MM(1, 0, b01); MM(1, 1, b23); __builtin_amdgcn_s_setprio(0);
        if (it < 3) { asm volatile("s_waitcnt vmcnt(4)"); }
        else        { asm volatile("s_waitcnt vmcnt(0)"); }
        BARP();
        // MP3: U row-0; stage A(T+2) both halves
        LDA(U, 0); LDB(U, 0, b01); LDB(U, 1, b23); STA(T + 2, 0); STA(T + 2, 1); BARP();
        __builtin_amdgcn_s_setprio(1); MM(0, 0, b01); MM(0, 1, b23); __builtin_amdgcn_s_setprio(0); BARP();
        // MP4: U row-1; stage B(T+3) both halves; wait A(T+2)/B(T+2)
        LDA(U, 1); STB(T + 3, 0); STB(T + 3, 1); BARP();
        __builtin_amdgcn_s_setprio(1); MM(1, 0, b01); MM(1, 1, b23); __builtin_amdgcn_s_setprio(0);
        if (it < 3) { asm volatile("s_waitcnt vmcnt(4)"); }
        BARP();
    }

    // full-fence boundary before LDS reuse in the epilogue
    __syncthreads();

    // ---- epilogue: sig multiply + row/col max + batched atomics ----
    int rq = hi4 * 4;
    int gcb = n0 + wn * 64;
    int qq = gcb / 192;
    int tb = gcb - qq * 192;
    (void)qq;
    const float* sg = sig + (size_t)l * 36864;

    float rowm[8][4];
    float colm[2][4];
    #pragma unroll
    for (int mi = 0; mi < 8; mi++)
        #pragma unroll
        for (int r = 0; r < 4; r++) rowm[mi][r] = -3.4e38f;
    #pragma unroll
    for (int h = 0; h < 2; h++)
        #pragma unroll
        for (int nj = 0; nj < 4; nj++) colm[h][nj] = -3.4e38f;

    #pragma unroll
    for (int mi = 0; mi < 8; mi++) {
        int gm = m0 + wm * 128 + mi * 16;
        int sb = gm % 192;
        #pragma unroll
        for (int r = 0; r < 4; r++) {
            const float* sp = sg + (size_t)(sb + rq + r) * 192 + tb;
            #pragma unroll
            for (int nj = 0; nj < 4; nj++) {
                float v = acc[mi][nj][r] * sp[nj * 16 + c];
                rowm[mi][r] = fmaxf(rowm[mi][r], v);
                colm[mi >> 2][nj] = fmaxf(colm[mi >> 2][nj], v);
            }
        }
    }
    #pragma unroll
    for (int st = 1; st <= 8; st <<= 1)
        #pragma unroll
        for (int mi = 0; mi < 8; mi++)
            #pragma unroll
            for (int r = 0; r < 4; r++)
                rowm[mi][r] = fmaxf(rowm[mi][r], __shfl_xor(rowm[mi][r], st));
    #pragma unroll
    for (int h = 0; h < 2; h++)
        #pragma unroll
        for (int nj = 0; nj < 4; nj++) {
            colm[h][nj] = fmaxf(colm[h][nj], __shfl_xor(colm[h][nj], 16));
            colm[h][nj] = fmaxf(colm[h][nj], __shfl_xor(colm[h][nj], 32));
        }

    unsigned* red = (unsigned*)smem;   // reuse GEMM LDS (all reads done)
    if (c == 0) {
        #pragma unroll
        for (int mi = 0; mi < 8; mi++)
            #pragma unroll
            for (int r = 0; r < 4; r++)
                red[w * 256 + mi * 16 + rq + r] = fkey(rowm[mi][r]);
    }
    if (lane < 16) {
        #pragma unroll
        for (int h = 0; h < 2; h++)
            #pragma unroll
            for (int nj = 0; nj < 4; nj++)
                red[w * 256 + 128 + h * 64 + nj * 16 + lane] = fkey(colm[h][nj]);
    }
    __syncthreads();
    #pragma unroll
    for (int pass = 0; pass < 4; pass++) {
        int flat = pass * 512 + tid;
        unsigned val = red[flat];
        int ww = flat >> 8;
        int rem = flat & 255;
        int wmf = ww >> 2, wnf = ww & 3;
        int gcbf = n0 + wnf * 64;
        int qqf = gcbf / 192;
        size_t addr;
        if (rem < 128) {           // smax: row-max (over t), s-indexed -> 2*jp+1
            int gmf = m0 + wmf * 128 + rem;
            int kkf = gmf / 192;
            int sf = gmf - kkf * 192;
            addr = ((size_t)l * 512 + 2 * (qqf * 16 + kkf) + 1) * 192 + sf;
        } else {                   // tmax: col-max (over s), t-indexed -> 2*jp
            int ii = rem - 128;
            int hh = ii >> 6, cc = ii & 63;
            int kkf = (m0 + wmf * 128 + hh * 64) / 192;
            addr = ((size_t)l * 512 + 2 * (qqf * 16 + kkf)) * 192 + (gcbf - qqf * 192) + cc;
        }
        atomicMax(&xkey[addr], val);
    }
}

// ---------------- K3a: bn1 partial stats ----------------
__global__ __launch_bounds__(256) void k_bn1s(const unsigned* __restrict__ xkey,
                                              float* __restrict__ bn1acc) {
    int l = blockIdx.x / 48;
    int b = blockIdx.x - l * 48;
    const unsigned* xk = xkey + (size_t)l * 98304 + b * 2048;
    int tid = threadIdx.x;
    uint4 v1 = *(const uint4*)(xk + tid * 8);
    uint4 v2 = *(const uint4*)(xk + tid * 8 + 4);
    float s = 0.f, s2 = 0.f;
    float e;
    e = funkey(v1.x); s += e; s2 += e * e;
    e = funkey(v1.y); s += e; s2 += e * e;
    e = funkey(v1.z); s += e; s2 += e * e;
    e = funkey(v1.w); s += e; s2 += e * e;
    e = funkey(v2.x); s += e; s2 += e * e;
    e = funkey(v2.y); s += e; s2 += e * e;
    e = funkey(v2.z); s += e; s2 += e * e;
    e = funkey(v2.w); s += e; s2 += e * e;
    #pragma unroll
    for (int o = 32; o; o >>= 1) { s += __shfl_down(s, o); s2 += __shfl_down(s2, o); }
    if ((tid & 63) == 0) {
        atomicAdd(&bn1acc[l * 2], s);
        atomicAdd(&bn1acc[l * 2 + 1], s2);
    }
}

// ---------------- K3b: bn1 normalize -> fp16 x ----------------
__global__ __launch_bounds__(256) void k_bn1n(const unsigned* __restrict__ xkey,
                                              const float* __restrict__ bn1acc,
                                              const float* __restrict__ g1,
                                              const float* __restrict__ b1,
                                              _Float16* __restrict__ xh) {
    int idx = blockIdx.x * 256 + threadIdx.x;   // x4 elements
    int l = idx / 24576;
    float mu = bn1acc[l * 2] * (1.f / 98304.f);
    float var = bn1acc[l * 2 + 1] * (1.f / 98304.f) - mu * mu;
    float a1 = g1[l] * rsqrtf(var + EPS_);
    float c1 = b1[l] - mu * a1;
    uint4 kv = *(const uint4*)(xkey + (size_t)idx * 4);
    _Float16 h[4];
    h[0] = (_Float16)(funkey(kv.x) * a1 + c1);
    h[1] = (_Float16)(funkey(kv.y) * a1 + c1);
    h[2] = (_Float16)(funkey(kv.z) * a1 + c1);
    h[3] = (_Float16)(funkey(kv.w) * a1 + c1);
    *(uint2*)(xh + (size_t)idx * 4) = *(uint2*)h;
}

// ---------------- K4: fc2 fp16 GEMM + fused bn2 partial stats ----------------
__global__ __launch_bounds__(256) void k_fc2(const _Float16* __restrict__ xh,
                                             const _Float16* __restrict__ w2h,
                                             const float* __restrict__ b2,
                                             _Float16* __restrict__ hb,
                                             float* __restrict__ bn2sum,
                                             float* __restrict__ bn2sq) {
    int bid = blockIdx.x;
    int l = bid >> 6;
    int rem = bid & 63;
    int mt = rem & 3, nt = rem >> 2;
    int m0 = mt * 128, n0 = nt * 128;
    const char* Ag = (const char*)(xh + (size_t)l * 98304);
    const char* Bg = (const char*)(w2h + (size_t)l * 393216);

    __shared__ __align__(16) char As[8192];
    __shared__ __align__(16) char Bs[8192];

    int tid = threadIdx.x;
    int lane = tid & 63;
    int w = tid >> 6;
    int wm = w >> 1, wn = w & 1;

    f32x4 acc[4][4];
    #pragma unroll
    for (int mi = 0; mi < 4; mi++)
        #pragma unroll
        for (int nj = 0; nj < 4; nj++)
            #pragma unroll
            for (int r = 0; r < 4; r++) acc[mi][nj][r] = 0.f;

    int srow = lane >> 2;
    int sseg = ((lane & 3) ^ ((srow >> 1) & 3)) * 16;
    int c = lane & 15;
    int kqp = (((lane >> 4) ^ ((c >> 1) & 3))) * 16;

    for (int d0 = 0; d0 < 384; d0 += 64) {
        __syncthreads();
        #pragma unroll
        for (int j = 0; j < 2; j++) {
            int r = w * 32 + j * 16 + srow;
            gld16(Ag + (size_t)(m0 + r) * 384 + d0 + sseg, As + (w * 32 + j * 16) * 64);
            gld16(Bg + (size_t)(n0 + r) * 384 + d0 + sseg, Bs + (w * 32 + j * 16) * 64);
        }
        __syncthreads();
        fp16x8 a[4], b[4];
        #pragma unroll
        for (int mi = 0; mi < 4; mi++)
            a[mi] = *(const fp16x8*)(As + (wm * 64 + mi * 16 + c) * 64 + kqp);
        #pragma unroll
        for (int nj = 0; nj < 4; nj++)
            b[nj] = *(const fp16x8*)(Bs + (wn * 64 + nj * 16 + c) * 64 + kqp);
        #pragma unroll
        for (int mi = 0; mi < 4; mi++)
            #pragma unroll
            for (int nj = 0; nj < 4; nj++)
                acc[mi][nj] = __builtin_amdgcn_mfma_f32_16x16x32_f16(a[mi], b[nj], acc[mi][nj], 0, 0, 0);
    }

    int rq = (lane >> 4) * 4;
    _Float16* ho = hb + (size_t)l * 1048576;
    float colsum[4], colsq[4];
    #pragma unroll
    for (int nj = 0; nj < 4; nj++) { colsum[nj] = 0.f; colsq[nj] = 0.f; }
    #pragma unroll
    for (int nj = 0; nj < 4; nj++) {
        int gf = n0 + wn * 64 + nj * 16 + c;
        float bias = b2[l * 2048 + gf];
        #pragma unroll
        for (int mi = 0; mi < 4; mi++) {
            #pragma unroll
            for (int r = 0; r < 4; r++) {
                int gm = m0 + wm * 64 + mi * 16 + rq + r;
                float v = acc[mi][nj][r] + bias;
                ho[(size_t)gm * 2048 + gf] = (_Float16)v;
                colsum[nj] += v;
                colsq[nj] += v * v;
            }
        }
    }
    #pragma unroll
    for (int nj = 0; nj < 4; nj++) {
        colsum[nj] += __shfl_xor(colsum[nj], 16);
        colsum[nj] += __shfl_xor(colsum[nj], 32);
        colsq[nj]  += __shfl_xor(colsq[nj], 16);
        colsq[nj]  += __shfl_xor(colsq[nj], 32);
    }
    if (lane < 16) {
        #pragma unroll
        for (int nj = 0; nj < 4; nj++) {
            int gf = n0 + wn * 64 + nj * 16 + lane;
            atomicAdd(&bn2sum[l * 2048 + gf], colsum[nj]);
            atomicAdd(&bn2sq[l * 2048 + gf], colsq[nj]);
        }
    }
}

// ---------------- K6: bn2(inline coef) + relu + fc3 dot (1 wave / row) -----
__global__ __launch_bounds__(256) void k_fc3(const _Float16* __restrict__ hb,
                                             const float* __restrict__ bn2sum,
                                             const float* __restrict__ bn2sq,
                                             const float* __restrict__ g2,
                                             const float* __restrict__ bb2,
                                             const float* __restrict__ w3,
                                             const float* __restrict__ b3,
                                             float* __restrict__ ybuf) {
    int grp = blockIdx.x & 63;
    int l = blockIdx.x >> 6;
    int tid = threadIdx.x;
    int w = tid >> 6, lane = tid & 63;
    const float* s1p = bn2sum + l * 2048;
    const float* s2p = bn2sq + l * 2048;
    const float* g2p = g2 + l * 2048;
    const float* b2p = bb2 + l * 2048;
    const float* w3p = w3 + l * 2048;
    #pragma unroll
    for (int rr = 0; rr < 2; rr++) {
        int n = grp * 8 + w + rr * 4;
        const _Float16* h = hb + ((size_t)l * 512 + n) * 2048;
        float sum = 0.f;
        #pragma unroll
        for (int q = 0; q < 4; q++) {
            int f = q * 512 + lane * 8;
            fp16x8 hv = *(const fp16x8*)(h + f);
            float4 u0 = *(const float4*)(s1p + f), u1 = *(const float4*)(s1p + f + 4);
            float4 q0 = *(const float4*)(s2p + f), q1 = *(const float4*)(s2p + f + 4);
            float4 g0 = *(const float4*)(g2p + f), g1 = *(const float4*)(g2p + f + 4);
            float4 c0 = *(const float4*)(b2p + f), c1 = *(const float4*)(b2p + f + 4);
            float4 w0 = *(const float4*)(w3p + f), w1 = *(const float4*)(w3p + f + 4);
            float vs[8] = {u0.x, u0.y, u0.z, u0.w, u1.x, u1.y, u1.z, u1.w};
            float vq[8] = {q0.x, q0.y, q0.z, q0.w, q1.x, q1.y, q1.z, q1.w};
            float vg[8] = {g0.x, g0.y, g0.z, g0.w, g1.x, g1.y, g1.z, g1.w};
            float vb[8] = {c0.x, c0.y, c0.z, c0.w, c1.x, c1.y, c1.z, c1.w};
            float vw[8] = {w0.x, w0.y, w0.z, w0.w, w1.x, w1.y, w1.z, w1.w};
            #pragma unroll
            for (int j = 0; j < 8; j++) {
                float mu = vs[j] * (1.f / 512.f);
                float var = vq[j] * (1.f / 512.f) - mu * mu;
                float a2 = vg[j] * rsqrtf(var + EPS_);
                float c2 = vb[j] - mu * a2;
                float v = (float)hv[j] * a2 + c2;
                v = fmaxf(v, 0.f);
                sum += v * vw[j];
            }
        }
        #pragma unroll
        for (int o = 32; o; o >>= 1) sum += __shfl_down(sum, o);
        if (lane == 0) ybuf[l * 512 + n] = sum + b3[l];
    }
}

// ---------------- K7: pair-sum + bn3 + layer-sum + pair_labels ----------------
__global__ __launch_bounds__(256) void k_final(const float* __restrict__ ybuf,
                                               const float* __restrict__ g3,
                                               const float* __restrict__ bb3,
                                               const int* __restrict__ targets,
                                               float* __restrict__ out) {
    int tid = threadIdx.x;
    __shared__ float red[8];
    float scoreacc = 0.f;
    for (int l = 0; l < 8; l++) {
        float z = ybuf[l * 512 + 2 * tid] + ybuf[l * 512 + 2 * tid + 1];
        float s = z, s2 = z * z;
        int lane = tid & 63, w = tid >> 6;
        #pragma unroll
        for (int o = 32; o; o >>= 1) { s += __shfl_down(s, o); s2 += __shfl_down(s2, o); }
        if (lane == 0) { red[w] = s; red[4 + w] = s2; }
        __syncthreads();
        float S1 = red[0] + red[1] + red[2] + red[3];
        float S2 = red[4] + red[5] + red[6] + red[7];
        float mu = S1 * (1.f / 256.f);
        float var = S2 * (1.f / 256.f) - mu * mu;
        float rstd = rsqrtf(var + EPS_);
        scoreacc += g3[l] * (z - mu) * rstd + bb3[l];
        __syncthreads();
    }
    out[tid] = scoreacc;
    int i = tid >> 4, j = tid & 15;
    out[256 + tid] = (targets[i] == targets[j]) ? 1.f : 0.f;
}

extern "C" void kernel_launch(void* const* d_in, const int* in_sizes, int n_in,
                              void* d_out, int out_size, void* d_ws, size_t ws_size,
                              hipStream_t stream) {
    const float* q_feat = (const float*)d_in[0];
    const float* g_feat = (const float*)d_in[1];
    const int*   targets = (const int*)d_in[2];
    const float* se     = (const float*)d_in[3];
    const float* fc0_w  = (const float*)d_in[4];
    const float* fc0_b  = (const float*)d_in[5];
    const float* bn1_g  = (const float*)d_in[6];
    const float* bn1_b  = (const float*)d_in[7];
    const float* fc2_w  = (const float*)d_in[8];
    const float* fc2_b  = (const float*)d_in[9];
    const float* bn2_g  = (const float*)d_in[10];
    const float* bn2_b  = (const float*)d_in[11];
    const float* fc3_w  = (const float*)d_in[12];
    const float* fc3_b  = (const float*)d_in[13];
    const float* bn3_g  = (const float*)d_in[14];
    const float* bn3_b  = (const float*)d_in[15];

    float* ws = (float*)d_ws;
    _Float16* Qh   = (_Float16*)ws;
    float*    sig  = ws + 12582912;
    unsigned* xkey = (unsigned*)(ws + 12877824);
    _Float16* xh   = (_Float16*)(ws + 13664256);
    _Float16* w2h  = (_Float16*)(ws + 14057472);
    _Float16* hb   = (_Float16*)(ws + 15630336);
    _Float16* w0h  = (_Float16*)(ws + 15630336);   // overlaid on hb (free until k_fc2)
    float* bn2sum = ws + 19824640;
    float* bn2sq  = ws + 19841024;
    float* bn1acc = ws + 19857408;
    float* ybuf   = ws + 19857424;
    float* out  = (float*)d_out;

    k_prep<<<2305, 256, 0, stream>>>(se, sig, fc2_w, w2h, xkey, bn2sum, fc0_w, w0h);
    k_fc0<<<1024, 512, 0, stream>>>(q_feat, g_feat, w0h, fc0_b, Qh);
    k_score<<<1152, 512, 0, stream>>>(Qh, sig, xkey, 0);
    k_bn1s<<<384, 256, 0, stream>>>(xkey, bn1acc);
    k_bn1n<<<768, 256, 0, stream>>>(xkey, bn1acc, bn1_g, bn1_b, xh);
    k_fc2<<<512, 256, 0, stream>>>(xh, w2h, fc2_b, hb, bn2sum, bn2sq);
    k_fc3<<<512, 256, 0, stream>>>(hb, bn2sum, bn2sq, bn2_g, bn2_b, fc3_w, fc3_b, ybuf);
    k_final<<<1, 256, 0, stream>>>(ybuf, bn3_g, bn3_b, targets, out);
}

// Round 15
// 366.189 us; speedup vs baseline: 1.0284x; 1.0284x over previous
//
#include <hip/hip_runtime.h>
#include <hip/hip_bf16.h>

// TransMatch round 21 (final consolidation = round-19 exact, 371.5 us verified):
//  - k_score: 256x256 8-phase counted-vmcnt pipeline (110 us, 0 conflicts).
//    Round-20's 4-mega-phase variant was neutral-to-negative (111.1) ->
//    barrier count is not the binding cost; reverted.
//  - k_fc0: M=192xN=128 2-blocks/CU + coalesced epilogue (68 us).
//  - k_prep merged (sigmoid + w2/w0 cvt + zeroing), inline-coef k_fc3.
//
// ws layout (float words):
//   Qh   fp16 [2][8][3072][512]  @ 0          = 12,582,912 f
//   sig  f32  [8][192][192]      @ 12,582,912 =    294,912 f
//   xkey u32  [8][512][192]      @ 12,877,824 =    786,432 f
//   xh   fp16 [8][512][192]      @ 13,664,256 =    393,216 f
//   w2h  fp16 [8][2048][192]     @ 14,057,472 =  1,572,864 f
//   hb   fp16 [8][512][2048]     @ 15,630,336 =  4,194,304 f   (w0h overlaid until k_fc2)
//   bn2sum f32 [8][2048]         @ 19,824,640 =     16,384 f
//   bn2sq  f32 [8][2048]         @ 19,841,024 =     16,384 f
//   bn1acc f32 [8][2]            @ 19,857,408 =         16 f
//   ybuf f32 [8][512]            @ 19,857,424 =      4,096 f

#define EPS_ 1e-5f

typedef __attribute__((ext_vector_type(8))) _Float16 fp16x8;
typedef __attribute__((ext_vector_type(4)))  float   f32x4;
typedef __attribute__((ext_vector_type(16))) float   f32x16;

__device__ __forceinline__ unsigned fkey(float f) {
    unsigned u = __float_as_uint(f);
    return (u & 0x80000000u) ? ~u : (u | 0x80000000u);
}
__device__ __forceinline__ float funkey(unsigned k) {
    return (k & 0x80000000u) ? __uint_as_float(k & 0x7FFFFFFFu)
                             : __uint_as_float(~k);
}
__device__ __forceinline__ void gld16(const void* gp, void* lp) {
    __builtin_amdgcn_global_load_lds(
        (const __attribute__((address_space(1))) unsigned*)gp,
        (__attribute__((address_space(3))) unsigned*)lp, 16, 0, 0);
}

// ---- K_prep: sigmoid(se) + w2 cvt + w0 cvt(pre-swizzled) + zeroing ----
__global__ __launch_bounds__(256) void k_prep(const float* __restrict__ se,
                                              float* __restrict__ sig,
                                              const float* __restrict__ w2,
                                              _Float16* __restrict__ w2h,
                                              unsigned* __restrict__ xkey,
                                              float* __restrict__ bn2z,
                                              const float* __restrict__ w0,
                                              _Float16* __restrict__ w0h) {
    int b = blockIdx.x;
    int tid = threadIdx.x;
    if (b < 768) {              // w2 fp32 -> fp16: 786432 float4 total, 4/thread
        size_t base = (size_t)b * 1024 + tid;     // float4 units
        #pragma unroll
        for (int k = 0; k < 4; k++) {
            size_t i = base + k * 256;
            float4 v = ((const float4*)w2)[i];
            _Float16 h[4] = {(_Float16)v.x, (_Float16)v.y, (_Float16)v.z, (_Float16)v.w};
            ((uint2*)w2h)[i] = *(uint2*)h;
        }
    } else if (b < 1056) {      // sigmoid (294912 elems, 288 blocks)
        int i = (b - 768) * 256 + tid;
        float4 v = *(const float4*)(se + (size_t)i * 4);
        float4 o;
        o.x = 1.f / (1.f + __expf(-v.x));
        o.y = 1.f / (1.f + __expf(-v.y));
        o.z = 1.f / (1.f + __expf(-v.z));
        o.w = 1.f / (1.f + __expf(-v.w));
        *(float4*)(sig + (size_t)i * 4) = o;
    } else if (b < 1248) {      // xkey zero: 786432 words, 192 blocks
        int i = (b - 1056) * 256 + tid;
        uint4 z = {0u, 0u, 0u, 0u};
        uint4* p = (uint4*)xkey + (size_t)i * 4;
        p[0] = z; p[1] = z; p[2] = z; p[3] = z;
    } else if (b < 1281) {      // bn2sum/bn2sq/bn1acc zero (33 blocks)
        int i = (b - 1248) * 256 + tid;
        if (i < 8196) {
            float4 z = {0.f, 0.f, 0.f, 0.f};
            *(float4*)(bn2z + (size_t)i * 4) = z;
        }
    } else {                    // w0 cvt: chunk ((l*8+ks)*512+e)*8 + (ch^(e&7))
        int g = (b - 1281) * 256 + tid;   // 0..262143
        int l  = g >> 15;
        int r  = g & 32767;
        int ks = r >> 12;
        int rr = r & 4095;
        int e  = rr >> 3;
        int ch = rr & 7;
        const float* src = w0 + (size_t)l * 262144 + (size_t)e * 512 + ks * 64 + ch * 8;
        float4 v0 = *(const float4*)src;
        float4 v1 = *(const float4*)(src + 4);
        fp16x8 h;
        h[0] = (_Float16)v0.x; h[1] = (_Float16)v0.y; h[2] = (_Float16)v0.z; h[3] = (_Float16)v0.w;
        h[4] = (_Float16)v1.x; h[5] = (_Float16)v1.y; h[6] = (_Float16)v1.z; h[7] = (_Float16)v1.w;
        size_t dst = ((size_t)(l * 8 + ks) * 512 + e) * 8 + (ch ^ (e & 7));
        *(fp16x8*)(w0h + dst * 8) = h;
    }
}

// ---------------- K1: fc0 -- M=192 x N=128 x K=512 fp16 GEMM ----------------
// (round-14 verified body; LDS 80 KiB -> 2 blocks/CU; coalesced epilogue)
__global__ __launch_bounds__(512, 4) void k_fc0(const float* __restrict__ qfeat,
                                                const float* __restrict__ gfeat,
                                                const _Float16* __restrict__ w0h,
                                                const float* __restrict__ b0,
                                                _Float16* __restrict__ Qh) {
    int bid = blockIdx.x;
    int blo = bid & 7;
    int et  = (bid >> 3) & 3;
    int bhi = (bid >> 5) & 1;
    int sel = (bid >> 6) & 1;
    int l   = bid >> 7;
    int b   = blo + bhi * 8;

    const float* feat = sel ? gfeat : qfeat;
    const float* Af = feat + (size_t)b * 786432 + (size_t)l * 98304;

    __shared__ __align__(16) char smem[81920];
    // A: [2 buf][192 rows][128 B] @ 0 (49152); W: [2 buf][128 rows][128 B] @ 49152

    int tid = threadIdx.x;
    int lane = tid & 63;
    int w = tid >> 6;
    int wm = w >> 2, wn = w & 3;     // 2 x 4 wave grid
    int c = lane & 15;
    int hi4 = lane >> 4;

    // A staging: slot s (0..1535) -> chunk = s/192, t = s%192; 3 slots/thread.
    int s0 = tid, s1 = tid + 512, s2 = tid + 1024;
    int ch0 = s0 / 192, t0 = s0 - ch0 * 192;
    int ch1 = s1 / 192, t1 = s1 - ch1 * 192;
    int ch2 = s2 / 192, t2 = s2 - ch2 * 192;
    const float* ap0 = Af + ch0 * 1536 + t0;
    const float* ap1 = Af + ch1 * 1536 + t1;
    const float* ap2 = Af + ch2 * 1536 + t2;
    int aw0 = t0 * 128 + ((ch0 ^ (t0 & 7)) << 4);
    int aw1 = t1 * 128 + ((ch1 ^ (t1 & 7)) << 4);
    int aw2 = t2 * 128 + ((ch2 ^ (t2 & 7)) << 4);

    f32x4 acc[6][2];
    #pragma unroll
    for (int mi = 0; mi < 6; mi++)
        #pragma unroll
        for (int nj = 0; nj < 2; nj++)
            #pragma unroll
            for (int r = 0; r < 4; r++) acc[mi][nj][r] = 0.f;

    float rA[3][8];

    auto ALOAD = [&](int ks) {
        int off = ks * 12288;       // d0*192
        #pragma unroll
        for (int j = 0; j < 8; j++) rA[0][j] = ap0[off + j * 192];
        #pragma unroll
        for (int j = 0; j < 8; j++) rA[1][j] = ap1[off + j * 192];
        #pragma unroll
        for (int j = 0; j < 8; j++) rA[2][j] = ap2[off + j * 192];
    };
    auto WLOAD = [&](int ks, int buf) {
        const _Float16* wp = w0h + ((size_t)(l * 8 + ks) * 512 + et * 128) * 64;
        char* d = smem + 49152 + buf * 16384;
        #pragma unroll
        for (int p = 0; p < 2; p++)
            gld16(wp + (size_t)(tid + p * 512) * 8, d + (tid + p * 512) * 16);
    };
    auto AWRITE = [&](int buf) {
        char* db = smem + buf * 24576;
        fp16x8 h0, h1, h2;
        #pragma unroll
        for (int j = 0; j < 8; j++) h0[j] = (_Float16)rA[0][j];
        #pragma unroll
        for (int j = 0; j < 8; j++) h1[j] = (_Float16)rA[1][j];
        #pragma unroll
        for (int j = 0; j < 8; j++) h2[j] = (_Float16)rA[2][j];
        *(fp16x8*)(db + aw0) = h0;
        *(fp16x8*)(db + aw1) = h1;
        *(fp16x8*)(db + aw2) = h2;
    };
    auto COMPUTE = [&](int buf) {
        const char* Ab = smem + buf * 24576;
        const char* Wb = smem + 49152 + buf * 16384;
        fp16x8 afr[6][2], bfr[2][2];
        #pragma unroll
        for (int mi = 0; mi < 6; mi++) {
            int tr = wm * 96 + mi * 16 + c;
            #pragma unroll
            for (int k2 = 0; k2 < 2; k2++) {
                int ph = (k2 * 4 + hi4) ^ (tr & 7);
                afr[mi][k2] = *(const fp16x8*)(Ab + tr * 128 + ph * 16);
            }
        }
        #pragma unroll
        for (int nj = 0; nj < 2; nj++) {
            int er = wn * 32 + nj * 16 + c;
            #pragma unroll
            for (int k2 = 0; k2 < 2; k2++) {
                int ph = (k2 * 4 + hi4) ^ (er & 7);
                bfr[nj][k2] = *(const fp16x8*)(Wb + er * 128 + ph * 16);
            }
        }
        #pragma unroll
        for (int k2 = 0; k2 < 2; k2++)
            #pragma unroll
            for (int mi = 0; mi < 6; mi++)
                #pragma unroll
                for (int nj = 0; nj < 2; nj++)
                    acc[mi][nj] = __builtin_amdgcn_mfma_f32_16x16x32_f16(
                        afr[mi][k2], bfr[nj][k2], acc[mi][nj], 0, 0, 0);
    };

    // prologue: stage K-step 0
    ALOAD(0); WLOAD(0, 0); AWRITE(0);
    __syncthreads();
    #pragma unroll
    for (int ks = 0; ks < 8; ks++) {
        int cur = ks & 1, nxt = cur ^ 1;
        if (ks < 7) { ALOAD(ks + 1); WLOAD(ks + 1, nxt); }
        COMPUTE(cur);
        if (ks < 7) AWRITE(nxt);
        __syncthreads();
    }

    // ---- coalesced epilogue: acc+bias -> LDS [192][128] fp16 -> 16B stores
    __syncthreads();
    _Float16* lb = (_Float16*)smem;
    int rq = hi4 * 4;
    #pragma unroll
    for (int nj = 0; nj < 2; nj++) {
        int col = wn * 32 + nj * 16 + c;
        float bias = b0[l * 512 + et * 128 + col];
        #pragma unroll
        for (int mi = 0; mi < 6; mi++) {
            int tb = wm * 96 + mi * 16 + rq;
            #pragma unroll
            for (int r = 0; r < 4; r++)
                lb[(tb + r) * 128 + col] = (_Float16)(acc[mi][nj][r] + bias);
        }
    }
    __syncthreads();
    _Float16* Ob = Qh + ((size_t)(sel * 8 + l) * 16 + b) * 98304 + et * 128;
    #pragma unroll
    for (int p = 0; p < 6; p++) {
        int v = tid + p * 512;          // vec8 index, 0..3071
        int t = v >> 4;                 // row 0..191
        int e = (v & 15) * 8;           // col 0..120
        *(fp16x8*)(Ob + (size_t)t * 512 + e) = *(const fp16x8*)(lb + t * 128 + e);
    }
}

// ---------------- K2: score GEMM, 256x256 tile, 8-phase pipeline ----------
#define BARP() do { __builtin_amdgcn_s_barrier(); \
                    __builtin_amdgcn_sched_barrier(0); } while (0)

__global__ __launch_bounds__(512, 2) void k_score(const _Float16* __restrict__ Qh,
                                                  const float* __restrict__ sig,
                                                  unsigned* __restrict__ xkey,
                                                  int base) {
    int bid = blockIdx.x + base;
    int l = bid & 7;           // layer-per-XCD (grid total = 8 * 144)
    int tau = bid >> 3;        // 0..143
    int mt = tau % 12;
    int nt = tau / 12;
    int m0 = mt * 256, n0 = nt * 256;

    const char* Ag = (const char*)(Qh + (size_t)(8 + l) * 1572864);  // key
    const char* Bg = (const char*)(Qh + (size_t)l * 1572864);        // query

    __shared__ __align__(16) char smem[131072];

    int tid = threadIdx.x;
    int lane = tid & 63;
    int w = tid >> 6;          // 0..7
    int wm = w >> 2, wn = w & 3;
    int c = lane & 15;
    int hi4 = lane >> 4;       // 0..3

    // fragment ds-read addressing (swizzled)
    int pk0 = ((hi4)     ^ (c & 7)) * 16;   // ks=0 logical chunk ^ row&7
    int pk1 = ((4 + hi4) ^ (c & 7)) * 16;   // ks=1
    char* aBase = smem + wm * 16384 + c * 128;
    char* bBase = smem + 65536 + (wn >> 1) * 16384 + ((wn & 1) * 64 + c) * 128;

    // staging addressing: lane -> row (lane>>3), phys chunk (lane&7);
    // global source pre-applies the inverse swizzle.
    int rl = lane >> 3;
    int qsw = ((lane & 7) ^ rl) * 16;
    const char* Asrc = Ag + (size_t)(m0 + w * 8 + rl) * 1024 + qsw;
    const char* Bsrc = Bg + (size_t)(n0 + w * 8 + rl) * 1024 + qsw;
    char* aSt = smem + w * 1024;
    char* bSt = smem + 65536 + w * 1024;

    f32x4 acc[8][4];
    #pragma unroll
    for (int mi = 0; mi < 8; mi++)
        #pragma unroll
        for (int nj = 0; nj < 4; nj++)
            #pragma unroll
            for (int r = 0; r < 4; r++) acc[mi][nj][r] = 0.f;

    fp16x8 a[4][2], b01[2][2], b23[2][2];

    auto STA = [&](int t, int h) {   // stage A half-tile (16 KB, 2 loads/thread)
        if (t < 8) {
            const char* s = Asrc + (size_t)(h * 128) * 1024 + t * 128;
            char* d = aSt + (t & 1) * 32768 + h * 16384;
            gld16(s, d);
            gld16(s + 64 * 1024, d + 8192);
        }
    };
    auto STB = [&](int t, int h) {
        if (t < 8) {
            const char* s = Bsrc + (size_t)(h * 128) * 1024 + t * 128;
            char* d = bSt + (t & 1) * 32768 + h * 16384;
            gld16(s, d);
            gld16(s + 64 * 1024, d + 8192);
        }
    };
    auto LDA = [&](int t, int mh) {  // a[mi 0..3][ks] for mi = mh*4..mh*4+3
        const char* p = aBase + (t & 1) * 32768 + mh * 8192;
        #pragma unroll
        for (int m = 0; m < 4; m++) {
            a[m][0] = *(const fp16x8*)(p + m * 2048 + pk0);
            a[m][1] = *(const fp16x8*)(p + m * 2048 + pk1);
        }
    };
    auto LDB = [&](int t, int nh, fp16x8 (&bb)[2][2]) {
        const char* p = bBase + (t & 1) * 32768 + nh * 4096;
        #pragma unroll
        for (int n = 0; n < 2; n++) {
            bb[n][0] = *(const fp16x8*)(p + n * 2048 + pk0);
            bb[n][1] = *(const fp16x8*)(p + n * 2048 + pk1);
        }
    };
    auto MM = [&](int mh, int nh, fp16x8 (&bb)[2][2]) {
        #pragma unroll
        for (int ks = 0; ks < 2; ks++)
            #pragma unroll
            for (int m = 0; m < 4; m++)
                #pragma unroll
                for (int n = 0; n < 2; n++)
                    acc[mh * 4 + m][nh * 2 + n] = __builtin_amdgcn_mfma_f32_16x16x32_f16(
                        a[m][ks], bb[n][ks], acc[mh * 4 + m][nh * 2 + n], 0, 0, 0);
    };

    // prologue: tile0 (B then A), then B(1); leave B(1) (4 loads) in flight
    STB(0, 0); STB(0, 1); STA(0, 0); STA(0, 1); STB(1, 0); STB(1, 1);
    asm volatile("s_waitcnt vmcnt(4)");
    BARP();

    #pragma unroll
    for (int it = 0; it < 4; it++) {
        int T = 2 * it, U = 2 * it + 1;
        // phase 1: quadrant (0,0) of T; stage A0(U)
        LDA(T, 0); LDB(T, 0, b01); STA(U, 0); BARP();
        __builtin_amdgcn_s_setprio(1); MM(0, 0, b01); __builtin_amdgcn_s_setprio(0); BARP();
        // phase 2: quadrant (0,1); stage A1(U)
        LDB(T, 1, b23); STA(U, 1); BARP();
        __builtin_amdgcn_s_setprio(1); MM(0, 1, b23); __builtin_amdgcn_s_setprio(0); BARP();
        // phase 3: quadrant (1,0); stage B0(T+2)
        LDA(T, 1); STB(T + 2, 0); BARP();
        __builtin_amdgcn_s_setprio(1); MM(1, 0, b01); __builtin_amdgcn_s_setprio(0); BARP();
        // phase 4: quadrant (1,1); stage B1(T+2); counted wait for tile U
        STB(T + 2, 1); BARP();
        __builtin_amdgcn_s_setprio(1); MM(1, 1, b23); __builtin_amdgcn_s_setprio(0);
        if (it < 3) { asm volatile("s_waitcnt vmcnt(4)"); }
        else        { asm volatile("s_waitcnt vmcnt(0)"); }
        BARP();
        // phase 5: quadrant (0,0) of U; stage A0(T+2)
        LDA(U, 0); LDB(U, 0, b01); STA(T + 2, 0); BARP();
        __builtin_amdgcn_s_setprio(1); MM(0, 0, b01); __builtin_amdgcn_s_setprio(0); BARP();
        // phase 6: quadrant (0,1); stage A1(T+2)
        LDB(U, 1, b23); STA(T + 2, 1); BARP();
        __builtin_amdgcn_s_setprio(1); MM(0, 1, b23); __builtin_amdgcn_s_setprio(0); BARP();
        // phase 7: quadrant (1,0); stage B0(T+3)
        LDA(U, 1); STB(T + 3, 0); BARP();
        __builtin_amdgcn_s_setprio(1); MM(1, 0, b01); __builtin_amdgcn_s_setprio(0); BARP();
        // phase 8: quadrant (1,1); stage B1(T+3); counted wait for tile T+2
        STB(T + 3, 1); BARP();
        __builtin_amdgcn_s_setprio(1); MM(1, 1, b23); __builtin_amdgcn_s_setprio(0);
        if (it < 3) { asm volatile("s_waitcnt vmcnt(4)"); }
        BARP();
    }

    // full-fence boundary before LDS reuse in the epilogue
    __syncthreads();

    // ---- epilogue: sig multiply + row/col max + batched atomics ----
    int rq = hi4 * 4;
    int gcb = n0 + wn * 64;
    int qq = gcb / 192;
    int tb = gcb - qq * 192;
    (void)qq;
    const float* sg = sig + (size_t)l * 36864;

    float rowm[8][4];
    float colm[2][4];
    #pragma unroll
    for (int mi = 0; mi < 8; mi++)
        #pragma unroll
        for (int r = 0; r < 4; r++) rowm[mi][r] = -3.4e38f;
    #pragma unroll
    for (int h = 0; h < 2; h++)
        #pragma unroll
        for (int nj = 0; nj < 4; nj++) colm[h][nj] = -3.4e38f;

    #pragma unroll
    for (int mi = 0; mi < 8; mi++) {
        int gm = m0 + wm * 128 + mi * 16;
        int sb = gm % 192;
        #pragma unroll
        for (int r = 0; r < 4; r++) {
            const float* sp = sg + (size_t)(sb + rq + r) * 192 + tb;
            #pragma unroll
            for (int nj = 0; nj < 4; nj++) {
                float v = acc[mi][nj][r] * sp[nj * 16 + c];
                rowm[mi][r] = fmaxf(rowm[mi][r], v);
                colm[mi >> 2][nj] = fmaxf(colm[mi >> 2][nj], v);
            }
        }
    }
    #pragma unroll
    for (int st = 1; st <= 8; st <<= 1)
        #pragma unroll
        for (int mi = 0; mi < 8; mi++)
            #pragma unroll
            for (int r = 0; r < 4; r++)
                rowm[mi][r] = fmaxf(rowm[mi][r], __shfl_xor(rowm[mi][r], st));
    #pragma unroll
    for (int h = 0; h < 2; h++)
        #pragma unroll
        for (int nj = 0; nj < 4; nj++) {
            colm[h][nj] = fmaxf(colm[h][nj], __shfl_xor(colm[h][nj], 16));
            colm[h][nj] = fmaxf(colm[h][nj], __shfl_xor(colm[h][nj], 32));
        }

    unsigned* red = (unsigned*)smem;   // reuse GEMM LDS (all reads done)
    if (c == 0) {
        #pragma unroll
        for (int mi = 0; mi < 8; mi++)
            #pragma unroll
            for (int r = 0; r < 4; r++)
                red[w * 256 + mi * 16 + rq + r] = fkey(rowm[mi][r]);
    }
    if (lane < 16) {
        #pragma unroll
        for (int h = 0; h < 2; h++)
            #pragma unroll
            for (int nj = 0; nj < 4; nj++)
                red[w * 256 + 128 + h * 64 + nj * 16 + lane] = fkey(colm[h][nj]);
    }
    __syncthreads();
    #pragma unroll
    for (int pass = 0; pass < 4; pass++) {
        int flat = pass * 512 + tid;
        unsigned val = red[flat];
        int ww = flat >> 8;
        int rem = flat & 255;
        int wmf = ww >> 2, wnf = ww & 3;
        int gcbf = n0 + wnf * 64;
        int qqf = gcbf / 192;
        size_t addr;
        if (rem < 128) {           // smax: row-max (over t), s-indexed -> 2*jp+1
            int gmf = m0 + wmf * 128 + rem;
            int kkf = gmf / 192;
            int sf = gmf - kkf * 192;
            addr = ((size_t)l * 512 + 2 * (qqf * 16 + kkf) + 1) * 192 + sf;
        } else {                   // tmax: col-max (over s), t-indexed -> 2*jp
            int ii = rem - 128;
            int hh = ii >> 6, cc = ii & 63;
            int kkf = (m0 + wmf * 128 + hh * 64) / 192;
            addr = ((size_t)l * 512 + 2 * (qqf * 16 + kkf)) * 192 + (gcbf - qqf * 192) + cc;
        }
        atomicMax(&xkey[addr], val);
    }
}

// ---------------- K3a: bn1 partial stats ----------------
__global__ __launch_bounds__(256) void k_bn1s(const unsigned* __restrict__ xkey,
                                              float* __restrict__ bn1acc) {
    int l = blockIdx.x / 48;
    int b = blockIdx.x - l * 48;
    const unsigned* xk = xkey + (size_t)l * 98304 + b * 2048;
    int tid = threadIdx.x;
    uint4 v1 = *(const uint4*)(xk + tid * 8);
    uint4 v2 = *(const uint4*)(xk + tid * 8 + 4);
    float s = 0.f, s2 = 0.f;
    float e;
    e = funkey(v1.x); s += e; s2 += e * e;
    e = funkey(v1.y); s += e; s2 += e * e;
    e = funkey(v1.z); s += e; s2 += e * e;
    e = funkey(v1.w); s += e; s2 += e * e;
    e = funkey(v2.x); s += e; s2 += e * e;
    e = funkey(v2.y); s += e; s2 += e * e;
    e = funkey(v2.z); s += e; s2 += e * e;
    e = funkey(v2.w); s += e; s2 += e * e;
    #pragma unroll
    for (int o = 32; o; o >>= 1) { s += __shfl_down(s, o); s2 += __shfl_down(s2, o); }
    if ((tid & 63) == 0) {
        atomicAdd(&bn1acc[l * 2], s);
        atomicAdd(&bn1acc[l * 2 + 1], s2);
    }
}

// ---------------- K3b: bn1 normalize -> fp16 x ----------------
__global__ __launch_bounds__(256) void k_bn1n(const unsigned* __restrict__ xkey,
                                              const float* __restrict__ bn1acc,
                                              const float* __restrict__ g1,
                                              const float* __restrict__ b1,
                                              _Float16* __restrict__ xh) {
    int idx = blockIdx.x * 256 + threadIdx.x;   // x4 elements
    int l = idx / 24576;
    float mu = bn1acc[l * 2] * (1.f / 98304.f);
    float var = bn1acc[l * 2 + 1] * (1.f / 98304.f) - mu * mu;
    float a1 = g1[l] * rsqrtf(var + EPS_);
    float c1 = b1[l] - mu * a1;
    uint4 kv = *(const uint4*)(xkey + (size_t)idx * 4);
    _Float16 h[4];
    h[0] = (_Float16)(funkey(kv.x) * a1 + c1);
    h[1] = (_Float16)(funkey(kv.y) * a1 + c1);
    h[2] = (_Float16)(funkey(kv.z) * a1 + c1);
    h[3] = (_Float16)(funkey(kv.w) * a1 + c1);
    *(uint2*)(xh + (size_t)idx * 4) = *(uint2*)h;
}

// ---------------- K4: fc2 fp16 GEMM + fused bn2 partial stats ----------------
__global__ __launch_bounds__(256) void k_fc2(const _Float16* __restrict__ xh,
                                             const _Float16* __restrict__ w2h,
                                             const float* __restrict__ b2,
                                             _Float16* __restrict__ hb,
                                             float* __restrict__ bn2sum,
                                             float* __restrict__ bn2sq) {
    int bid = blockIdx.x;
    int l = bid >> 6;
    int rem = bid & 63;
    int mt = rem & 3, nt = rem >> 2;
    int m0 = mt * 128, n0 = nt * 128;
    const char* Ag = (const char*)(xh + (size_t)l * 98304);
    const char* Bg = (const char*)(w2h + (size_t)l * 393216);

    __shared__ __align__(16) char As[8192];
    __shared__ __align__(16) char Bs[8192];

    int tid = threadIdx.x;
    int lane = tid & 63;
    int w = tid >> 6;
    int wm = w >> 1, wn = w & 1;

    f32x4 acc[4][4];
    #pragma unroll
    for (int mi = 0; mi < 4; mi++)
        #pragma unroll
        for (int nj = 0; nj < 4; nj++)
            #pragma unroll
            for (int r = 0; r < 4; r++) acc[mi][nj][r] = 0.f;

    int srow = lane >> 2;
    int sseg = ((lane & 3) ^ ((srow >> 1) & 3)) * 16;
    int c = lane & 15;
    int kqp = (((lane >> 4) ^ ((c >> 1) & 3))) * 16;

    for (int d0 = 0; d0 < 384; d0 += 64) {
        __syncthreads();
        #pragma unroll
        for (int j = 0; j < 2; j++) {
            int r = w * 32 + j * 16 + srow;
            gld16(Ag + (size_t)(m0 + r) * 384 + d0 + sseg, As + (w * 32 + j * 16) * 64);
            gld16(Bg + (size_t)(n0 + r) * 384 + d0 + sseg, Bs + (w * 32 + j * 16) * 64);
        }
        __syncthreads();
        fp16x8 a[4], b[4];
        #pragma unroll
        for (int mi = 0; mi < 4; mi++)
            a[mi] = *(const fp16x8*)(As + (wm * 64 + mi * 16 + c) * 64 + kqp);
        #pragma unroll
        for (int nj = 0; nj < 4; nj++)
            b[nj] = *(const fp16x8*)(Bs + (wn * 64 + nj * 16 + c) * 64 + kqp);
        #pragma unroll
        for (int mi = 0; mi < 4; mi++)
            #pragma unroll
            for (int nj = 0; nj < 4; nj++)
                acc[mi][nj] = __builtin_amdgcn_mfma_f32_16x16x32_f16(a[mi], b[nj], acc[mi][nj], 0, 0, 0);
    }

    int rq = (lane >> 4) * 4;
    _Float16* ho = hb + (size_t)l * 1048576;
    float colsum[4], colsq[4];
    #pragma unroll
    for (int nj = 0; nj < 4; nj++) { colsum[nj] = 0.f; colsq[nj] = 0.f; }
    #pragma unroll
    for (int nj = 0; nj < 4; nj++) {
        int gf = n0 + wn * 64 + nj * 16 + c;
        float bias = b2[l * 2048 + gf];
        #pragma unroll
        for (int mi = 0; mi < 4; mi++) {
            #pragma unroll
            for (int r = 0; r < 4; r++) {
                int gm = m0 + wm * 64 + mi * 16 + rq + r;
                float v = acc[mi][nj][r] + bias;
                ho[(size_t)gm * 2048 + gf] = (_Float16)v;
                colsum[nj] += v;
                colsq[nj] += v * v;
            }
        }
    }
    #pragma unroll
    for (int nj = 0; nj < 4; nj++) {
        colsum[nj] += __shfl_xor(colsum[nj], 16);
        colsum[nj] += __shfl_xor(colsum[nj], 32);
        colsq[nj]  += __shfl_xor(colsq[nj], 16);
        colsq[nj]  += __shfl_xor(colsq[nj], 32);
    }
    if (lane < 16) {
        #pragma unroll
        for (int nj = 0; nj < 4; nj++) {
            int gf = n0 + wn * 64 + nj * 16 + lane;
            atomicAdd(&bn2sum[l * 2048 + gf], colsum[nj]);
            atomicAdd(&bn2sq[l * 2048 + gf], colsq[nj]);
        }
    }
}

// ---------------- K6: bn2(inline coef) + relu + fc3 dot (1 wave / row) -----
__global__ __launch_bounds__(256) void k_fc3(const _Float16* __restrict__ hb,
                                             const float* __restrict__ bn2sum,
                                             const float* __restrict__ bn2sq,
                                             const float* __restrict__ g2,
                                             const float* __restrict__ bb2,
                                             const float* __restrict__ w3,
                                             const float* __restrict__ b3,
                                             float* __restrict__ ybuf) {
    int grp = blockIdx.x & 63;
    int l = blockIdx.x >> 6;
    int tid = threadIdx.x;
    int w = tid >> 6, lane = tid & 63;
    const float* s1p = bn2sum + l * 2048;
    const float* s2p = bn2sq + l * 2048;
    const float* g2p = g2 + l * 2048;
    const float* b2p = bb2 + l * 2048;
    const float* w3p = w3 + l * 2048;
    #pragma unroll
    for (int rr = 0; rr < 2; rr++) {
        int n = grp * 8 + w + rr * 4;
        const _Float16* h = hb + ((size_t)l * 512 + n) * 2048;
        float sum = 0.f;
        #pragma unroll
        for (int q = 0; q < 4; q++) {
            int f = q * 512 + lane * 8;
            fp16x8 hv = *(const fp16x8*)(h + f);
            float4 u0 = *(const float4*)(s1p + f), u1 = *(const float4*)(s1p + f + 4);
            float4 q0 = *(const float4*)(s2p + f), q1 = *(const float4*)(s2p + f + 4);
            float4 g0 = *(const float4*)(g2p + f), g1 = *(const float4*)(g2p + f + 4);
            float4 c0 = *(const float4*)(b2p + f), c1 = *(const float4*)(b2p + f + 4);
            float4 w0 = *(const float4*)(w3p + f), w1 = *(const float4*)(w3p + f + 4);
            float vs[8] = {u0.x, u0.y, u0.z, u0.w, u1.x, u1.y, u1.z, u1.w};
            float vq[8] = {q0.x, q0.y, q0.z, q0.w, q1.x, q1.y, q1.z, q1.w};
            float vg[8] = {g0.x, g0.y, g0.z, g0.w, g1.x, g1.y, g1.z, g1.w};
            float vb[8] = {c0.x, c0.y, c0.z, c0.w, c1.x, c1.y, c1.z, c1.w};
            float vw[8] = {w0.x, w0.y, w0.z, w0.w, w1.x, w1.y, w1.z, w1.w};
            #pragma unroll
            for (int j = 0; j < 8; j++) {
                float mu = vs[j] * (1.f / 512.f);
                float var = vq[j] * (1.f / 512.f) - mu * mu;
                float a2 = vg[j] * rsqrtf(var + EPS_);
                float c2 = vb[j] - mu * a2;
                float v = (float)hv[j] * a2 + c2;
                v = fmaxf(v, 0.f);
                sum += v * vw[j];
            }
        }
        #pragma unroll
        for (int o = 32; o; o >>= 1) sum += __shfl_down(sum, o);
        if (lane == 0) ybuf[l * 512 + n] = sum + b3[l];
    }
}

// ---------------- K7: pair-sum + bn3 + layer-sum + pair_labels ----------------
__global__ __launch_bounds__(256) void k_final(const float* __restrict__ ybuf,
                                               const float* __restrict__ g3,
                                               const float* __restrict__ bb3,
                                               const int* __restrict__ targets,
                                               float* __restrict__ out) {
    int tid = threadIdx.x;
    __shared__ float red[8];
    float scoreacc = 0.f;
    for (int l = 0; l < 8; l++) {
        float z = ybuf[l * 512 + 2 * tid] + ybuf[l * 512 + 2 * tid + 1];
        float s = z, s2 = z * z;
        int lane = tid & 63, w = tid >> 6;
        #pragma unroll
        for (int o = 32; o; o >>= 1) { s += __shfl_down(s, o); s2 += __shfl_down(s2, o); }
        if (lane == 0) { red[w] = s; red[4 + w] = s2; }
        __syncthreads();
        float S1 = red[0] + red[1] + red[2] + red[3];
        float S2 = red[4] + red[5] + red[6] + red[7];
        float mu = S1 * (1.f / 256.f);
        float var = S2 * (1.f / 256.f) - mu * mu;
        float rstd = rsqrtf(var + EPS_);
        scoreacc += g3[l] * (z - mu) * rstd + bb3[l];
        __syncthreads();
    }
    out[tid] = scoreacc;
    int i = tid >> 4, j = tid & 15;
    out[256 + tid] = (targets[i] == targets[j]) ? 1.f : 0.f;
}

extern "C" void kernel_launch(void* const* d_in, const int* in_sizes, int n_in,
                              void* d_out, int out_size, void* d_ws, size_t ws_size,
                              hipStream_t stream) {
    const float* q_feat = (const float*)d_in[0];
    const float* g_feat = (const float*)d_in[1];
    const int*   targets = (const int*)d_in[2];
    const float* se     = (const float*)d_in[3];
    const float* fc0_w  = (const float*)d_in[4];
    const float* fc0_b  = (const float*)d_in[5];
    const float* bn1_g  = (const float*)d_in[6];
    const float* bn1_b  = (const float*)d_in[7];
    const float* fc2_w  = (const float*)d_in[8];
    const float* fc2_b  = (const float*)d_in[9];
    const float* bn2_g  = (const float*)d_in[10];
    const float* bn2_b  = (const float*)d_in[11];
    const float* fc3_w  = (const float*)d_in[12];
    const float* fc3_b  = (const float*)d_in[13];
    const float* bn3_g  = (const float*)d_in[14];
    const float* bn3_b  = (const float*)d_in[15];

    float* ws = (float*)d_ws;
    _Float16* Qh   = (_Float16*)ws;
    float*    sig  = ws + 12582912;
    unsigned* xkey = (unsigned*)(ws + 12877824);
    _Float16* xh   = (_Float16*)(ws + 13664256);
    _Float16* w2h  = (_Float16*)(ws + 14057472);
    _Float16* hb   = (_Float16*)(ws + 15630336);
    _Float16* w0h  = (_Float16*)(ws + 15630336);   // overlaid on hb (free until k_fc2)
    float* bn2sum = ws + 19824640;
    float* bn2sq  = ws + 19841024;
    float* bn1acc = ws + 19857408;
    float* ybuf   = ws + 19857424;
    float* out  = (float*)d_out;

    k_prep<<<2305, 256, 0, stream>>>(se, sig, fc2_w, w2h, xkey, bn2sum, fc0_w, w0h);
    k_fc0<<<1024, 512, 0, stream>>>(q_feat, g_feat, w0h, fc0_b, Qh);
    k_score<<<1152, 512, 0, stream>>>(Qh, sig, xkey, 0);
    k_bn1s<<<384, 256, 0, stream>>>(xkey, bn1acc);
    k_bn1n<<<768, 256, 0, stream>>>(xkey, bn1acc, bn1_g, bn1_b, xh);
    k_fc2<<<512, 256, 0, stream>>>(xh, w2h, fc2_b, hb, bn2sum, bn2sq);
    k_fc3<<<512, 256, 0, stream>>>(hb, bn2sum, bn2sq, bn2_g, bn2_b, fc3_w, fc3_b, ybuf);
    k_final<<<1, 256, 0, stream>>>(ybuf, bn3_g, bn3_b, targets, out);
}